// Round 8
// baseline (506.512 us; speedup 1.0000x reference)
//
#include <hip/hip_runtime.h>
#include <hip/hip_bf16.h>

typedef __bf16 bf16_t;
typedef __bf16 bf16x8 __attribute__((ext_vector_type(8)));
typedef float f32x4 __attribute__((ext_vector_type(4)));

// Problem constants
#define T_SEQ 3072
#define DIM 2048
#define NH 16
#define QLORA 1536
#define KVLORA 512
#define NOPE 128
#define ROPE 64
#define VDIM 128
#define HD 192          // NOPE+ROPE
#define SCALE 0.07216878364870323f  // 192^-0.5

// fused-buffer strides
#define T1KV_LD 2112    // [3072][1536 q_lat | 512 c_kv | 64 k_rope]
#define QNR_LD 3072     // [3072][2048 q_nope | 1024 q_rope]

// ---------------- helpers ----------------
__device__ inline float wave_reduce_sum(float v) {
    #pragma unroll
    for (int off = 32; off > 0; off >>= 1) v += __shfl_down(v, off);
    return v;
}

__device__ inline float block_reduce_sum_256(float v) {
    __shared__ float red[4];
    int lane = threadIdx.x & 63, w = threadIdx.x >> 6;
    v = wave_reduce_sum(v);
    if (lane == 0) red[w] = v;
    __syncthreads();
    if (threadIdx.x == 0) red[0] = red[0] + red[1] + red[2] + red[3];
    __syncthreads();
    return red[0];
}

// async global->LDS, 16B per lane. LDS dest is wave-uniform base + lane*16 (linear).
// Global source address is per-lane (pre-swizzle it to realize swizzled LDS layouts).
__device__ inline void glds16(const bf16_t* g, bf16_t* l) {
    __builtin_amdgcn_global_load_lds(
        (const __attribute__((address_space(1))) unsigned int*)g,
        (__attribute__((address_space(3))) unsigned int*)l, 16, 0, 0);
}

// ---------------- fp32 -> bf16 convert ----------------
__global__ void f2b_kernel(const float* __restrict__ in, bf16_t* __restrict__ out, int n) {
    int i = (blockIdx.x * 256 + threadIdx.x) * 4;
    if (i < n) {
        float4 v = *(const float4*)&in[i];
        bf16_t o[4] = {(bf16_t)v.x, (bf16_t)v.y, (bf16_t)v.z, (bf16_t)v.w};
        *(uint2*)&out[i] = *(const uint2*)o;
    }
}

// ---------------- fp32 [K][N] -> bf16 [N][K] transpose-convert ----------------
__global__ __launch_bounds__(256) void transp_kernel(
    const float* __restrict__ in, bf16_t* __restrict__ out, int K, int N)
{
    __shared__ float tile[32][33];
    int k0 = blockIdx.y * 32, n0 = blockIdx.x * 32;
    int tx = threadIdx.x & 31, ty = threadIdx.x >> 5;
    #pragma unroll
    for (int i = 0; i < 4; ++i)
        tile[ty + i * 8][tx] = in[(size_t)(k0 + ty + i * 8) * N + n0 + tx];
    __syncthreads();
    #pragma unroll
    for (int i = 0; i < 4; ++i)
        out[(size_t)(n0 + ty + i * 8) * K + k0 + tx] = (bf16_t)tile[tx][ty + i * 8];
}

// ---------------- bf16 kvu V-part -> vt[h][d][t] transpose ----------------
__global__ __launch_bounds__(256) void vt_transp(
    const bf16_t* __restrict__ kvu, bf16_t* __restrict__ vt)
{
    __shared__ bf16_t tile[32][34];
    int t0 = blockIdx.x * 32, d0 = blockIdx.y * 32, h = blockIdx.z;
    int tx = threadIdx.x & 31, ty = threadIdx.x >> 5;
    #pragma unroll
    for (int i = 0; i < 4; ++i)
        tile[ty + i * 8][tx] = kvu[(size_t)(t0 + ty + i * 8) * (NH * 256) + h * 256 + NOPE + d0 + tx];
    __syncthreads();
    #pragma unroll
    for (int i = 0; i < 4; ++i)
        vt[((size_t)h * VDIM + d0 + ty + i * 8) * T_SEQ + t0 + tx] = tile[tx][ty + i * 8];
}

// ---------------- MFMA GEMM: C[M,N] = A[M,K](bf16, row-stride lda) x Bt[N,K](bf16, row-stride ldb) ----------------
// 128x128 tile, BK=32, glds staging with LDS double-buffer + counted vmcnt(4).
__global__ __launch_bounds__(256) void gemm_mfma(
    const bf16_t* __restrict__ A, const bf16_t* __restrict__ Bt,
    float* __restrict__ Cf, bf16_t* __restrict__ Cb,
    int M, int N, int K, int lda, int ldb, int ldc, int writef)
{
    __shared__ __align__(16) bf16_t As[2][128 * 32];
    __shared__ __align__(16) bf16_t Bs[2][128 * 32];
    int tid = threadIdx.x;
    int w = tid >> 6, lane = tid & 63;
    int quad = lane >> 4, l16 = lane & 15;
    int bm = blockIdx.y * 128, bn = blockIdx.x * 128;
    int wm = (w & 1) * 64, wn = (w >> 1) * 64;

    // staging coords: thread stages rows srow and srow+64, 16B chunk soff
    int srow = tid >> 2, soff = (tid & 3) * 8;
    const bf16_t* a0 = A + (size_t)(bm + srow) * lda + soff;
    const bf16_t* a1 = A + (size_t)(bm + 64 + srow) * lda + soff;
    int br0 = bn + srow;      if (br0 >= N) br0 = N - 1;   // clamp (cols >= N never written)
    int br1 = bn + 64 + srow; if (br1 >= N) br1 = N - 1;
    const bf16_t* b0 = Bt + (size_t)br0 * ldb + soff;
    const bf16_t* b1 = Bt + (size_t)br1 * ldb + soff;

    f32x4 acc[4][4];
    #pragma unroll
    for (int i = 0; i < 4; ++i)
        #pragma unroll
        for (int j = 0; j < 4; ++j)
            acc[i][j] = (f32x4){0.f, 0.f, 0.f, 0.f};

    int nk = K >> 5;
    // prologue: stage tile 0 into buffer 0
    glds16(a0, &As[0][tid * 8]);
    glds16(a1, &As[0][tid * 8 + 2048]);
    glds16(b0, &Bs[0][tid * 8]);
    glds16(b1, &Bs[0][tid * 8 + 2048]);
    a0 += 32; a1 += 32; b0 += 32; b1 += 32;

    for (int t = 0; t < nk; ++t) {
        int cur = t & 1;
        if (t + 1 < nk) {
            int nxt = cur ^ 1;
            glds16(a0, &As[nxt][tid * 8]);
            glds16(a1, &As[nxt][tid * 8 + 2048]);
            glds16(b0, &Bs[nxt][tid * 8]);
            glds16(b1, &Bs[nxt][tid * 8 + 2048]);
            a0 += 32; a1 += 32; b0 += 32; b1 += 32;
            asm volatile("s_waitcnt vmcnt(4)" ::: "memory");   // tile t's 4 loads done
        } else {
            asm volatile("s_waitcnt vmcnt(0)" ::: "memory");   // drain for last tile
        }
        __builtin_amdgcn_s_barrier();          // all waves' tile-t loads landed
        __builtin_amdgcn_sched_barrier(0);     // no ds_read hoisted above barrier

        bf16x8 af[4], bfr[4];
        #pragma unroll
        for (int t4 = 0; t4 < 4; ++t4) {
            af[t4]  = *(const bf16x8*)&As[cur][(wm + t4 * 16 + l16) * 32 + quad * 8];
            bfr[t4] = *(const bf16x8*)&Bs[cur][(wn + t4 * 16 + l16) * 32 + quad * 8];
        }
        #pragma unroll
        for (int i = 0; i < 4; ++i)
            #pragma unroll
            for (int j = 0; j < 4; ++j)
                acc[i][j] = __builtin_amdgcn_mfma_f32_16x16x32_bf16(af[i], bfr[j], acc[i][j], 0, 0, 0);

        __builtin_amdgcn_sched_barrier(0);     // compute stays above trailing barrier
        __builtin_amdgcn_s_barrier();          // all waves done reading buf[cur]
        __builtin_amdgcn_sched_barrier(0);     // next STAGE not hoisted above it
    }

    #pragma unroll
    for (int i = 0; i < 4; ++i) {
        #pragma unroll
        for (int j = 0; j < 4; ++j) {
            #pragma unroll
            for (int r = 0; r < 4; ++r) {
                int row = bm + wm + i * 16 + quad * 4 + r;
                int col = bn + wn + j * 16 + l16;
                if (col < N) {
                    if (writef) Cf[(size_t)row * ldc + col] = acc[i][j][r];
                    else        Cb[(size_t)row * ldc + col] = (bf16_t)acc[i][j][r];
                }
            }
        }
    }
}

// ---------------- rmsnorm over first N cols of rows with stride ld ----------------
__global__ __launch_bounds__(256) void rmsnorm_rows(
    bf16_t* __restrict__ X, const float* __restrict__ w, int N, int ld)
{
    int row = blockIdx.x;
    bf16_t* x = X + (size_t)row * ld;
    float ss = 0.f;
    for (int i = threadIdx.x; i < N; i += 256) { float v = (float)x[i]; ss += v * v; }
    ss = block_reduce_sum_256(ss);
    float sc = rsqrtf(ss / (float)N + 1e-6f);
    for (int i = threadIdx.x; i < N; i += 256)
        x[i] = (bf16_t)((float)x[i] * sc * w[i]);
}

// ---------------- kv post: src = fused t1kv rows at col offset 1536 ----------------
__global__ __launch_bounds__(256) void kv_post(
    const bf16_t* __restrict__ kvd, const float* __restrict__ w,
    const float* __restrict__ freqs,
    bf16_t* __restrict__ ckvn, bf16_t* __restrict__ kr)
{
    int row = blockIdx.x;
    const bf16_t* src = kvd + (size_t)row * T1KV_LD;   // points at c_kv|k_rope block
    float ss = 0.f;
    for (int i = threadIdx.x; i < KVLORA; i += 256) { float v = (float)src[i]; ss += v * v; }
    ss = block_reduce_sum_256(ss);
    float sc = rsqrtf(ss / (float)KVLORA + 1e-6f);
    for (int i = threadIdx.x; i < KVLORA; i += 256)
        ckvn[(size_t)row * KVLORA + i] = (bf16_t)((float)src[i] * sc * w[i]);
    if (threadIdx.x < 32) {
        int i = threadIdx.x;
        float f = freqs[row * 32 + i];
        float c = cosf(f), s = sinf(f);
        float x1 = (float)src[KVLORA + 2 * i], x2 = (float)src[KVLORA + 2 * i + 1];
        kr[(size_t)row * ROPE + 2 * i]     = (bf16_t)(x1 * c - x2 * s);
        kr[(size_t)row * ROPE + 2 * i + 1] = (bf16_t)(x1 * s + x2 * c);
    }
}

// ---------------- rope on q_rope (cols 2048.. of qnr) in-place ----------------
__global__ void rope_q(bf16_t* __restrict__ qr, const float* __restrict__ freqs) {
    int idx = blockIdx.x * 256 + threadIdx.x;
    if (idx >= T_SEQ * NH * 32) return;
    int t = idx >> 9;
    int rem = idx & 511;
    int h = rem >> 5;
    int i = rem & 31;
    float f = freqs[t * 32 + i];
    float c = cosf(f), s = sinf(f);
    bf16_t* p = qr + (size_t)t * QNR_LD + h * ROPE + 2 * i;
    float x1 = (float)p[0], x2 = (float)p[1];
    p[0] = (bf16_t)(x1 * c - x2 * s);
    p[1] = (bf16_t)(x1 * s + x2 * c);
}

// ---------------- split-K MFMA flash attention (causal, fixed-max softmax) ----------------
// v11: latency-pipeline fix. v8/v10 both sat at ~121us with ~17% MfmaUtil: per-iter
// chain (glds issue -> vmcnt(0) drain in __syncthreads -> compute -> barrier) was
// ~6000 cyc fully exposed at ~1 wave/SIMD. v11 double-buffers 32-key HALF-tiles
// (LDS stays 50KB -> 3 blocks/CU like v8) with counted vmcnt(5): next half-tile's
// 5 glds stay in flight across both barriers (gemm_mfma's proven pattern). Keeps
// v10's qs=2 fragment reuse (128 q-rows/block). kt is in 32-key units.
#define PS_STRIDE 40    // 32+8 bf16
__global__ __launch_bounds__(256) void attn_v11(
    const bf16_t* __restrict__ QNR,
    const bf16_t* __restrict__ KVU, const bf16_t* __restrict__ KR,
    const bf16_t* __restrict__ Vt,
    bf16_t* __restrict__ Opart, float* __restrict__ lpart)
{
    __shared__ __align__(16) bf16_t Kn[2][32 * 128];       // 16384 B (k_nope, swizzled)
    __shared__ __align__(16) bf16_t Kr[2][32 * 64];        //  8192 B (k_rope, swizzled)
    __shared__ __align__(16) bf16_t Vs[2][128 * 32];       // 16384 B (v^T, swizzled)
    __shared__ __align__(16) bf16_t Ps[4][32 * PS_STRIDE]; // 10240 B   -> 50 KB total

    int qt2 = blockIdx.x, cx = blockIdx.y, h = blockIdx.z;
    int ktmax = 4 * qt2 + 4;            // causal bound in 32-key half-tiles
    int kt0 = cx * 24;                  // chunk = 24 half-tiles = 768 keys
    if (kt0 >= ktmax) return;
    int kt1 = min(ktmax, kt0 + 24);
    int g = qt2 / 6, r6 = qt2 - g * 6;  // nch(qt2) = g+1
    int slot = h * 60 + 3 * g * (g + 1) + r6 * (g + 1) + cx;

    int tid = threadIdx.x;
    int w = tid >> 6, lane = tid & 63;
    int quad = lane >> 4, l16 = lane & 15;
    int qbase = qt2 * 128;

    // Q fragments for both q-subtiles (rows qbase+qs*64+w*16+l16)
    bf16x8 qf[2][6];
    #pragma unroll
    for (int qs = 0; qs < 2; ++qs) {
        int qrow = qbase + qs * 64 + w * 16 + l16;
        #pragma unroll
        for (int kk = 0; kk < 4; ++kk)
            qf[qs][kk] = *(const bf16x8*)&QNR[(size_t)qrow * QNR_LD + h * NOPE + kk * 32 + quad * 8];
        #pragma unroll
        for (int kk = 4; kk < 6; ++kk)
            qf[qs][kk] = *(const bf16x8*)&QNR[(size_t)qrow * QNR_LD + (NH * NOPE) + h * ROPE + (kk - 4) * 32 + quad * 8];
    }

    // per-lane pre-swizzled global sources (rule-21: linear LDS dest; swizzle on
    // source AND read). Kn/Kr: phys chunk c holds logical chunk c^(row&7).
    // Vs rows have 4 chunks: phys chunk c holds logical c^((row>>1)&3).
    int l4 = lane >> 4, l3 = lane >> 3, l2 = lane >> 2;
    const bf16_t* kn0 = KVU + (size_t)(kt0 * 32 + w * 8 + l4) * (NH * 256) + h * 256 + ((lane & 15) ^ l4) * 8;
    const bf16_t* kn1 = KVU + (size_t)(kt0 * 32 + w * 8 + 4 + l4) * (NH * 256) + h * 256 + ((lane & 15) ^ (4 + l4)) * 8;
    const bf16_t* krp = KR + (size_t)(kt0 * 32 + w * 8 + l3) * ROPE + ((lane & 7) ^ l3) * 8;
    int vswz = (l2 >> 1) & 3;           // ((w*32 + i*16 + l2)>>1)&3 == (l2>>1)&3
    const bf16_t* vp0 = Vt + ((size_t)h * VDIM + w * 32 + l2) * T_SEQ + kt0 * 32 + ((lane & 3) ^ vswz) * 8;
    const bf16_t* vp1 = Vt + ((size_t)h * VDIM + w * 32 + 16 + l2) * T_SEQ + kt0 * 32 + ((lane & 3) ^ vswz) * 8;

    bf16x8 ones;
    #pragma unroll
    for (int i = 0; i < 8; ++i) ones[i] = (bf16_t)1.0f;

    f32x4 o[2][8];
    #pragma unroll
    for (int qs = 0; qs < 2; ++qs)
        #pragma unroll
        for (int nt = 0; nt < 8; ++nt) o[qs][nt] = (f32x4){0.f, 0.f, 0.f, 0.f};
    f32x4 lacc[2];
    lacc[0] = (f32x4){0.f, 0.f, 0.f, 0.f};
    lacc[1] = (f32x4){0.f, 0.f, 0.f, 0.f};

    // prologue: stage half-tile kt0 into buffer 0 (5 glds per thread)
    glds16(kn0, &Kn[0][(w * 2 + 0) * 512]);
    glds16(kn1, &Kn[0][(w * 2 + 1) * 512]);
    glds16(krp, &Kr[0][w * 512]);
    glds16(vp0, &Vs[0][(w * 2 + 0) * 512]);
    glds16(vp1, &Vs[0][(w * 2 + 1) * 512]);
    kn0 += (size_t)32 * NH * 256; kn1 += (size_t)32 * NH * 256;
    krp += 32 * ROPE; vp0 += 32; vp1 += 32;

    for (int kt = kt0; kt < kt1; ++kt) {
        int kbase = kt * 32;
        int cur = (kt - kt0) & 1;
        if (kt + 1 < kt1) {
            int nxt = cur ^ 1;
            // issue next half-tile's loads; they stay in flight across the barriers
            glds16(kn0, &Kn[nxt][(w * 2 + 0) * 512]);
            glds16(kn1, &Kn[nxt][(w * 2 + 1) * 512]);
            glds16(krp, &Kr[nxt][w * 512]);
            glds16(vp0, &Vs[nxt][(w * 2 + 0) * 512]);
            glds16(vp1, &Vs[nxt][(w * 2 + 1) * 512]);
            kn0 += (size_t)32 * NH * 256; kn1 += (size_t)32 * NH * 256;
            krp += 32 * ROPE; vp0 += 32; vp1 += 32;
            asm volatile("s_waitcnt vmcnt(5)" ::: "memory");   // tile kt's 5 landed
        } else {
            asm volatile("s_waitcnt vmcnt(0)" ::: "memory");   // drain last tile
        }
        __builtin_amdgcn_s_barrier();          // all waves' tile-kt data visible
        __builtin_amdgcn_sched_barrier(0);     // no ds_read hoisted above barrier

        // S = Q K^T : 2 col-tiles x (4 nope + 2 rope) k-steps; kf feeds both qs
        f32x4 S[2][2];
        #pragma unroll
        for (int qs = 0; qs < 2; ++qs)
            #pragma unroll
            for (int c = 0; c < 2; ++c) S[qs][c] = (f32x4){0.f, 0.f, 0.f, 0.f};
        #pragma unroll
        for (int kk = 0; kk < 4; ++kk) {
            #pragma unroll
            for (int c = 0; c < 2; ++c) {
                bf16x8 kf = *(const bf16x8*)&Kn[cur][(c * 16 + l16) * 128 + (((kk * 4 + quad) ^ (l16 & 7)) * 8)];
                S[0][c] = __builtin_amdgcn_mfma_f32_16x16x32_bf16(qf[0][kk], kf, S[0][c], 0, 0, 0);
                S[1][c] = __builtin_amdgcn_mfma_f32_16x16x32_bf16(qf[1][kk], kf, S[1][c], 0, 0, 0);
            }
        }
        #pragma unroll
        for (int kk = 4; kk < 6; ++kk) {
            #pragma unroll
            for (int c = 0; c < 2; ++c) {
                bf16x8 kf = *(const bf16x8*)&Kr[cur][(c * 16 + l16) * 64 + ((((kk - 4) * 4 + quad) ^ (l16 & 7)) * 8)];
                S[0][c] = __builtin_amdgcn_mfma_f32_16x16x32_bf16(qf[0][kk], kf, S[0][c], 0, 0, 0);
                S[1][c] = __builtin_amdgcn_mfma_f32_16x16x32_bf16(qf[1][kk], kf, S[1][c], 0, 0, 0);
            }
        }

        // fixed-max softmax: p = exp(s*SCALE) (bounded; shift-invariance -> additive splits)
        #pragma unroll
        for (int qs = 0; qs < 2; ++qs) {
            #pragma unroll
            for (int c = 0; c < 2; ++c) {
                #pragma unroll
                for (int j = 0; j < 4; ++j) {
                    int col = kbase + c * 16 + l16;
                    int grow = qbase + qs * 64 + w * 16 + quad * 4 + j;
                    float p = (col <= grow) ? __expf(S[qs][c][j] * SCALE) : 0.f;
                    Ps[w][(qs * 16 + quad * 4 + j) * PS_STRIDE + c * 16 + l16] = (bf16_t)p;
                }
            }
        }
        __asm__ volatile("s_waitcnt lgkmcnt(0)" ::: "memory");

        bf16x8 pf[2];
        #pragma unroll
        for (int qs = 0; qs < 2; ++qs) {
            pf[qs] = *(const bf16x8*)&Ps[w][(qs * 16 + l16) * PS_STRIDE + quad * 8];
            lacc[qs] = __builtin_amdgcn_mfma_f32_16x16x32_bf16(pf[qs], ones, lacc[qs], 0, 0, 0);
        }

        // O += P V : vf feeds both q-subtiles
        #pragma unroll
        for (int nt = 0; nt < 8; ++nt) {
            bf16x8 vf = *(const bf16x8*)&Vs[cur][(nt * 16 + l16) * 32 + ((quad ^ ((l16 >> 1) & 3)) * 8)];
            o[0][nt] = __builtin_amdgcn_mfma_f32_16x16x32_bf16(pf[0], vf, o[0][nt], 0, 0, 0);
            o[1][nt] = __builtin_amdgcn_mfma_f32_16x16x32_bf16(pf[1], vf, o[1][nt], 0, 0, 0);
        }
        __builtin_amdgcn_sched_barrier(0);     // compute stays above trailing barrier
        __builtin_amdgcn_s_barrier();          // all waves done reading buf[cur]
        __builtin_amdgcn_sched_barrier(0);     // next STAGE not hoisted above it
    }

    // write raw partials (no normalization); slot = 128 rows x 128 d
    #pragma unroll
    for (int qs = 0; qs < 2; ++qs) {
        #pragma unroll
        for (int nt = 0; nt < 8; ++nt)
            #pragma unroll
            for (int j = 0; j < 4; ++j)
                Opart[(size_t)slot * 16384 + (qs * 64 + w * 16 + quad * 4 + j) * 128 + nt * 16 + l16] = (bf16_t)o[qs][nt][j];
        if (l16 == 0) {
            #pragma unroll
            for (int j = 0; j < 4; ++j)
                lpart[slot * 128 + qs * 64 + w * 16 + quad * 4 + j] = lacc[qs][j];
        }
    }
}

// ---------------- combine: sum partials, normalize, write ao ----------------
// grid (24, 16), block 512. Thread: row r = tid/4 (0..127), 32 cols at (tid%4)*32.
__global__ __launch_bounds__(512) void attn_combine(
    const bf16_t* __restrict__ Opart, const float* __restrict__ lpart,
    bf16_t* __restrict__ AO)
{
    int qt2 = blockIdx.x, h = blockIdx.y;
    int g = qt2 / 6, r6 = qt2 - g * 6;
    int nch = g + 1;
    int base = h * 60 + 3 * g * (g + 1) + r6 * (g + 1);
    int r = threadIdx.x >> 2, c0 = (threadIdx.x & 3) * 32;

    float acc[32];
    #pragma unroll
    for (int i = 0; i < 32; ++i) acc[i] = 0.f;
    float lsum = 0.f;
    for (int ch = 0; ch < nch; ++ch) {
        int slot = base + ch;
        const bf16_t* p = &Opart[(size_t)slot * 16384 + r * 128 + c0];
        #pragma unroll
        for (int v = 0; v < 4; ++v) {
            bf16x8 u = *(const bf16x8*)&p[v * 8];
            #pragma unroll
            for (int e = 0; e < 8; ++e) acc[v * 8 + e] += (float)u[e];
        }
        lsum += lpart[slot * 128 + r];
    }
    float inv = 1.0f / lsum;
    bf16_t* dst = AO + (size_t)(qt2 * 128 + r) * (NH * VDIM) + h * VDIM + c0;
    #pragma unroll
    for (int v = 0; v < 4; ++v) {
        bf16_t tmp[8];
        #pragma unroll
        for (int e = 0; e < 8; ++e) tmp[e] = (bf16_t)(acc[v * 8 + e] * inv);
        *(uint4*)&dst[v * 8] = *(const uint4*)tmp;
    }
}

// ---------------- launch ----------------
extern "C" void kernel_launch(void* const* d_in, const int* in_sizes, int n_in,
                              void* d_out, int out_size, void* d_ws, size_t ws_size,
                              hipStream_t stream) {
    const float* x        = (const float*)d_in[0];
    const float* freqs    = (const float*)d_in[1];
    // d_in[2] = mask (unused; causality applied analytically)
    const float* wq_down  = (const float*)d_in[3];
    const float* q_norm_w = (const float*)d_in[4];
    const float* wq_nope  = (const float*)d_in[5];
    const float* wq_rope  = (const float*)d_in[6];
    const float* wkv_down = (const float*)d_in[7];
    const float* kv_norm_w= (const float*)d_in[8];
    const float* wkv_up   = (const float*)d_in[9];
    const float* wo       = (const float*)d_in[10];
    float* out = (float*)d_out;

    bf16_t* ws = (bf16_t*)d_ws;
    // ---- pool region (two time-disjoint views), 25,493,504 bf16 elems ----
    // A-view: pre-attention transients
    bf16_t* xb     = ws;                     // 3072*2048
    bf16_t* wqd_t  = xb     + 6291456;       // [1536][2048]  \ contiguous pair ->
    bf16_t* wkvd_t = wqd_t  + 3145728;       // [576][2048]   / fused Bt, N=2112
    bf16_t* wqn_t  = wkvd_t + 1179648;       // [2048][1536]  \ contiguous pair ->
    bf16_t* wqr_t  = wqn_t  + 3145728;       // [1024][1536]  / fused Bt, N=3072
    bf16_t* wkvu_t = wqr_t  + 1572864;       // [4096][512]
    bf16_t* t1kv   = wkvu_t + 2097152;       // [3072][2112] fused q_lat|c_kv|k_rope
    bf16_t* ckvn   = t1kv   + 6488064;       // 3072*512  (ends at 25,493,504)
    // B-view: attention partials + ao (960 slots x 16384 = same 15.73M footprint)
    bf16_t* Opart  = ws;                     // 960 slots * 16384
    float*  lpart  = (float*)(ws + 15728640);// 960 * 128 fp32
    bf16_t* ao     = ws + 15728640 + 245760; // 3072*2048
    // ---- tail region (long-lived) ----
    bf16_t* wo_t   = ws    + 25493504;       // [2048][2048]
    bf16_t* kr     = wo_t  + 4194304;        // 3072*64
    bf16_t* qnr    = kr    + 196608;         // [3072][3072] fused q_nope|q_rope
    bf16_t* kvu    = qnr   + 9437184;        // 3072*4096
    bf16_t* vt     = kvu   + 12582912;       // [16][128][3072]  (total 58,195,968)

    // converts + weight transposes
    f2b_kernel<<<T_SEQ * DIM / 4 / 256, 256, 0, stream>>>(x, xb, T_SEQ * DIM);
    transp_kernel<<<dim3(QLORA / 32, DIM / 32), 256, 0, stream>>>(wq_down, wqd_t, DIM, QLORA);
    transp_kernel<<<dim3((KVLORA + ROPE) / 32, DIM / 32), 256, 0, stream>>>(wkv_down, wkvd_t, DIM, KVLORA + ROPE);
    transp_kernel<<<dim3(NH * NOPE / 32, QLORA / 32), 256, 0, stream>>>(wq_nope, wqn_t, QLORA, NH * NOPE);
    transp_kernel<<<dim3(NH * ROPE / 32, QLORA / 32), 256, 0, stream>>>(wq_rope, wqr_t, QLORA, NH * ROPE);
    transp_kernel<<<dim3(NH * 256 / 32, KVLORA / 32), 256, 0, stream>>>(wkv_up, wkvu_t, KVLORA, NH * 256);
    transp_kernel<<<dim3(DIM / 32, DIM / 32), 256, 0, stream>>>(wo, wo_t, DIM, DIM);

    // fused down-projection: [q_lat | c_kv | k_rope], N=2112, grid 17x24=408
    gemm_mfma<<<dim3(17, T_SEQ / 128), 256, 0, stream>>>(
        xb, wqd_t, nullptr, t1kv, T_SEQ, 2112, DIM, DIM, DIM, T1KV_LD, 0);

    rmsnorm_rows<<<T_SEQ, 256, 0, stream>>>(t1kv, q_norm_w, QLORA, T1KV_LD);
    kv_post<<<T_SEQ, 256, 0, stream>>>(t1kv + QLORA, kv_norm_w, freqs, ckvn, kr);

    // fused q up-projection: [q_nope | q_rope], N=3072, grid 24x24=576
    gemm_mfma<<<dim3(24, T_SEQ / 128), 256, 0, stream>>>(
        t1kv, wqn_t, nullptr, qnr, T_SEQ, 3072, QLORA, T1KV_LD, QLORA, QNR_LD, 0);
    rope_q<<<(T_SEQ * NH * 32 + 255) / 256, 256, 0, stream>>>(qnr + NH * NOPE, freqs);

    // kv up-projection, grid 32x24=768
    gemm_mfma<<<dim3(NH * 256 / 128, T_SEQ / 128), 256, 0, stream>>>(
        ckvn, wkvu_t, nullptr, kvu, T_SEQ, NH * 256, KVLORA, KVLORA, KVLORA, NH * 256, 0);

    // V transpose for attention B-operand
    vt_transp<<<dim3(T_SEQ / 32, VDIM / 32, NH), 256, 0, stream>>>(kvu, vt);

    // split-K attention (128 q-rows/block, 32-key half-tiles, dbuf) + combine
    attn_v11<<<dim3(T_SEQ / 128, 4, NH), 256, 0, stream>>>(qnr, kvu, kr, vt, Opart, lpart);
    attn_combine<<<dim3(T_SEQ / 128, NH), 512, 0, stream>>>(Opart, lpart, ao);

    // output projection (fp32 out)
    gemm_mfma<<<dim3(DIM / 128, T_SEQ / 128), 256, 0, stream>>>(
        ao, wo_t, out, nullptr, T_SEQ, DIM, DIM, DIM, DIM, DIM, 1);
}

// Round 9
// 474.970 us; speedup vs baseline: 1.0664x; 1.0664x over previous
//
#include <hip/hip_runtime.h>
#include <hip/hip_bf16.h>

typedef __bf16 bf16_t;
typedef __bf16 bf16x8 __attribute__((ext_vector_type(8)));
typedef float f32x4 __attribute__((ext_vector_type(4)));

// Problem constants
#define T_SEQ 3072
#define DIM 2048
#define NH 16
#define QLORA 1536
#define KVLORA 512
#define NOPE 128
#define ROPE 64
#define VDIM 128
#define HD 192          // NOPE+ROPE
#define SCALE 0.07216878364870323f  // 192^-0.5
#define CHUNK 12        // k-tiles (of 64 keys) per attention chunk

// fused-buffer strides
#define T1KV_LD 2112    // [3072][1536 q_lat | 512 c_kv | 64 k_rope]
#define QNR_LD 3072     // [3072][2048 q_nope | 1024 q_rope]

// ---------------- helpers ----------------
__device__ inline float wave_reduce_sum(float v) {
    #pragma unroll
    for (int off = 32; off > 0; off >>= 1) v += __shfl_down(v, off);
    return v;
}

__device__ inline float block_reduce_sum_256(float v) {
    __shared__ float red[4];
    int lane = threadIdx.x & 63, w = threadIdx.x >> 6;
    v = wave_reduce_sum(v);
    if (lane == 0) red[w] = v;
    __syncthreads();
    if (threadIdx.x == 0) red[0] = red[0] + red[1] + red[2] + red[3];
    __syncthreads();
    return red[0];
}

// async global->LDS, 16B per lane. LDS dest is wave-uniform base + lane*16 (linear).
// Global source address is per-lane (pre-swizzle it to realize swizzled LDS layouts).
__device__ inline void glds16(const bf16_t* g, bf16_t* l) {
    __builtin_amdgcn_global_load_lds(
        (const __attribute__((address_space(1))) unsigned int*)g,
        (__attribute__((address_space(3))) unsigned int*)l, 16, 0, 0);
}

// ---------------- fp32 -> bf16 convert ----------------
__global__ void f2b_kernel(const float* __restrict__ in, bf16_t* __restrict__ out, int n) {
    int i = (blockIdx.x * 256 + threadIdx.x) * 4;
    if (i < n) {
        float4 v = *(const float4*)&in[i];
        bf16_t o[4] = {(bf16_t)v.x, (bf16_t)v.y, (bf16_t)v.z, (bf16_t)v.w};
        *(uint2*)&out[i] = *(const uint2*)o;
    }
}

// ---------------- fp32 [K][N] -> bf16 [N][K] transpose-convert ----------------
__global__ __launch_bounds__(256) void transp_kernel(
    const float* __restrict__ in, bf16_t* __restrict__ out, int K, int N)
{
    __shared__ float tile[32][33];
    int k0 = blockIdx.y * 32, n0 = blockIdx.x * 32;
    int tx = threadIdx.x & 31, ty = threadIdx.x >> 5;
    #pragma unroll
    for (int i = 0; i < 4; ++i)
        tile[ty + i * 8][tx] = in[(size_t)(k0 + ty + i * 8) * N + n0 + tx];
    __syncthreads();
    #pragma unroll
    for (int i = 0; i < 4; ++i)
        out[(size_t)(n0 + ty + i * 8) * K + k0 + tx] = (bf16_t)tile[tx][ty + i * 8];
}

// ---------------- bf16 kvu V-part -> vt[h][d][t] transpose ----------------
__global__ __launch_bounds__(256) void vt_transp(
    const bf16_t* __restrict__ kvu, bf16_t* __restrict__ vt)
{
    __shared__ bf16_t tile[32][34];
    int t0 = blockIdx.x * 32, d0 = blockIdx.y * 32, h = blockIdx.z;
    int tx = threadIdx.x & 31, ty = threadIdx.x >> 5;
    #pragma unroll
    for (int i = 0; i < 4; ++i)
        tile[ty + i * 8][tx] = kvu[(size_t)(t0 + ty + i * 8) * (NH * 256) + h * 256 + NOPE + d0 + tx];
    __syncthreads();
    #pragma unroll
    for (int i = 0; i < 4; ++i)
        vt[((size_t)h * VDIM + d0 + ty + i * 8) * T_SEQ + t0 + tx] = tile[tx][ty + i * 8];
}

// ---------------- MFMA GEMM: C[M,N] = A[M,K](bf16, row-stride lda) x Bt[N,K](bf16, row-stride ldb) ----------------
// 128x128 tile, BK=32, glds staging with LDS double-buffer + counted vmcnt(4).
__global__ __launch_bounds__(256) void gemm_mfma(
    const bf16_t* __restrict__ A, const bf16_t* __restrict__ Bt,
    float* __restrict__ Cf, bf16_t* __restrict__ Cb,
    int M, int N, int K, int lda, int ldb, int ldc, int writef)
{
    __shared__ __align__(16) bf16_t As[2][128 * 32];
    __shared__ __align__(16) bf16_t Bs[2][128 * 32];
    int tid = threadIdx.x;
    int w = tid >> 6, lane = tid & 63;
    int quad = lane >> 4, l16 = lane & 15;
    int bm = blockIdx.y * 128, bn = blockIdx.x * 128;
    int wm = (w & 1) * 64, wn = (w >> 1) * 64;

    // staging coords: thread stages rows srow and srow+64, 16B chunk soff
    int srow = tid >> 2, soff = (tid & 3) * 8;
    const bf16_t* a0 = A + (size_t)(bm + srow) * lda + soff;
    const bf16_t* a1 = A + (size_t)(bm + 64 + srow) * lda + soff;
    int br0 = bn + srow;      if (br0 >= N) br0 = N - 1;   // clamp (cols >= N never written)
    int br1 = bn + 64 + srow; if (br1 >= N) br1 = N - 1;
    const bf16_t* b0 = Bt + (size_t)br0 * ldb + soff;
    const bf16_t* b1 = Bt + (size_t)br1 * ldb + soff;

    f32x4 acc[4][4];
    #pragma unroll
    for (int i = 0; i < 4; ++i)
        #pragma unroll
        for (int j = 0; j < 4; ++j)
            acc[i][j] = (f32x4){0.f, 0.f, 0.f, 0.f};

    int nk = K >> 5;
    // prologue: stage tile 0 into buffer 0
    glds16(a0, &As[0][tid * 8]);
    glds16(a1, &As[0][tid * 8 + 2048]);
    glds16(b0, &Bs[0][tid * 8]);
    glds16(b1, &Bs[0][tid * 8 + 2048]);
    a0 += 32; a1 += 32; b0 += 32; b1 += 32;

    for (int t = 0; t < nk; ++t) {
        int cur = t & 1;
        if (t + 1 < nk) {
            int nxt = cur ^ 1;
            glds16(a0, &As[nxt][tid * 8]);
            glds16(a1, &As[nxt][tid * 8 + 2048]);
            glds16(b0, &Bs[nxt][tid * 8]);
            glds16(b1, &Bs[nxt][tid * 8 + 2048]);
            a0 += 32; a1 += 32; b0 += 32; b1 += 32;
            asm volatile("s_waitcnt vmcnt(4)" ::: "memory");   // tile t's 4 loads done
        } else {
            asm volatile("s_waitcnt vmcnt(0)" ::: "memory");   // drain for last tile
        }
        __builtin_amdgcn_s_barrier();          // all waves' tile-t loads landed
        __builtin_amdgcn_sched_barrier(0);     // no ds_read hoisted above barrier

        bf16x8 af[4], bfr[4];
        #pragma unroll
        for (int t4 = 0; t4 < 4; ++t4) {
            af[t4]  = *(const bf16x8*)&As[cur][(wm + t4 * 16 + l16) * 32 + quad * 8];
            bfr[t4] = *(const bf16x8*)&Bs[cur][(wn + t4 * 16 + l16) * 32 + quad * 8];
        }
        #pragma unroll
        for (int i = 0; i < 4; ++i)
            #pragma unroll
            for (int j = 0; j < 4; ++j)
                acc[i][j] = __builtin_amdgcn_mfma_f32_16x16x32_bf16(af[i], bfr[j], acc[i][j], 0, 0, 0);

        __builtin_amdgcn_sched_barrier(0);     // compute stays above trailing barrier
        __builtin_amdgcn_s_barrier();          // all waves done reading buf[cur]
        __builtin_amdgcn_sched_barrier(0);     // next STAGE not hoisted above it
    }

    #pragma unroll
    for (int i = 0; i < 4; ++i) {
        #pragma unroll
        for (int j = 0; j < 4; ++j) {
            #pragma unroll
            for (int r = 0; r < 4; ++r) {
                int row = bm + wm + i * 16 + quad * 4 + r;
                int col = bn + wn + j * 16 + l16;
                if (col < N) {
                    if (writef) Cf[(size_t)row * ldc + col] = acc[i][j][r];
                    else        Cb[(size_t)row * ldc + col] = (bf16_t)acc[i][j][r];
                }
            }
        }
    }
}

// ---------------- rmsnorm over first N cols of rows with stride ld ----------------
__global__ __launch_bounds__(256) void rmsnorm_rows(
    bf16_t* __restrict__ X, const float* __restrict__ w, int N, int ld)
{
    int row = blockIdx.x;
    bf16_t* x = X + (size_t)row * ld;
    float ss = 0.f;
    for (int i = threadIdx.x; i < N; i += 256) { float v = (float)x[i]; ss += v * v; }
    ss = block_reduce_sum_256(ss);
    float sc = rsqrtf(ss / (float)N + 1e-6f);
    for (int i = threadIdx.x; i < N; i += 256)
        x[i] = (bf16_t)((float)x[i] * sc * w[i]);
}

// ---------------- kv post: src = fused t1kv rows at col offset 1536 ----------------
__global__ __launch_bounds__(256) void kv_post(
    const bf16_t* __restrict__ kvd, const float* __restrict__ w,
    const float* __restrict__ freqs,
    bf16_t* __restrict__ ckvn, bf16_t* __restrict__ kr)
{
    int row = blockIdx.x;
    const bf16_t* src = kvd + (size_t)row * T1KV_LD;   // points at c_kv|k_rope block
    float ss = 0.f;
    for (int i = threadIdx.x; i < KVLORA; i += 256) { float v = (float)src[i]; ss += v * v; }
    ss = block_reduce_sum_256(ss);
    float sc = rsqrtf(ss / (float)KVLORA + 1e-6f);
    for (int i = threadIdx.x; i < KVLORA; i += 256)
        ckvn[(size_t)row * KVLORA + i] = (bf16_t)((float)src[i] * sc * w[i]);
    if (threadIdx.x < 32) {
        int i = threadIdx.x;
        float f = freqs[row * 32 + i];
        float c = cosf(f), s = sinf(f);
        float x1 = (float)src[KVLORA + 2 * i], x2 = (float)src[KVLORA + 2 * i + 1];
        kr[(size_t)row * ROPE + 2 * i]     = (bf16_t)(x1 * c - x2 * s);
        kr[(size_t)row * ROPE + 2 * i + 1] = (bf16_t)(x1 * s + x2 * c);
    }
}

// ---------------- rope on q_rope (cols 2048.. of qnr) in-place ----------------
__global__ void rope_q(bf16_t* __restrict__ qr, const float* __restrict__ freqs) {
    int idx = blockIdx.x * 256 + threadIdx.x;
    if (idx >= T_SEQ * NH * 32) return;
    int t = idx >> 9;
    int rem = idx & 511;
    int h = rem >> 5;
    int i = rem & 31;
    float f = freqs[t * 32 + i];
    float c = cosf(f), s = sinf(f);
    bf16_t* p = qr + (size_t)t * QNR_LD + h * ROPE + 2 * i;
    float x1 = (float)p[0], x2 = (float)p[1];
    p[0] = (bf16_t)(x1 * c - x2 * s);
    p[1] = (bf16_t)(x1 * s + x2 * c);
}

// ---------------- split-K MFMA flash attention (causal, fixed-max softmax) ----------------
// v12: v8's exact proven body (glds staging, rule-21 swizzle, 50KB LDS -> 3 blocks/CU
// static) with ONE change: qt enumerated in DESCENDING order. Block length varies
// 1..12 iterations with length increasing in qt; ascending dispatch put all the long
// blocks last -> low-occupancy tail (measured 18.6% vs 37.5% static cap). Longest-
// first dispatch packs short blocks into the gaps.
#define P_STRIDE 72     // 64+8 bf16
__device__ inline int slot_base(int qt, int h) {
    int b = qt / CHUNK;
    return h * 120 + qt + 6 * b * (b - 1) + (qt - CHUNK * b) * b;
}
__global__ __launch_bounds__(256) void attn_v12(
    const bf16_t* __restrict__ QNR,
    const bf16_t* __restrict__ KVU, const bf16_t* __restrict__ KR,
    const bf16_t* __restrict__ Vt,
    bf16_t* __restrict__ Opart, float* __restrict__ lpart)
{
    __shared__ __align__(16) bf16_t Kn[64 * 128];         // 16384 B (k_nope, swizzled)
    __shared__ __align__(16) bf16_t Kr[64 * 64];          //  8192 B (k_rope, swizzled)
    __shared__ __align__(16) bf16_t Vs[128 * 64];         // 16384 B (v^T, swizzled)
    __shared__ __align__(16) bf16_t Ps[4][16 * P_STRIDE]; //  9216 B  -> 50176 B total

    int qt = (T_SEQ / 64 - 1) - blockIdx.x;   // DESCENDING: longest blocks first
    int cx = blockIdx.y, h = blockIdx.z;
    if (cx > qt / CHUNK) return;
    int slot = slot_base(qt, h) + cx;
    int kt0 = cx * CHUNK;
    int kt1 = min(qt + 1, kt0 + CHUNK);

    int tid = threadIdx.x;
    int w = tid >> 6, lane = tid & 63;
    int quad = lane >> 4, l16 = lane & 15;
    int qbase = qt * 64;

    // Q fragments straight from global into registers (fused layout)
    bf16x8 qf[6];
    {
        int qrow = qbase + w * 16 + l16;
        #pragma unroll
        for (int kk = 0; kk < 4; ++kk)
            qf[kk] = *(const bf16x8*)&QNR[(size_t)qrow * QNR_LD + h * NOPE + kk * 32 + quad * 8];
        #pragma unroll
        for (int kk = 4; kk < 6; ++kk)
            qf[kk] = *(const bf16x8*)&QNR[(size_t)qrow * QNR_LD + (NH * NOPE) + h * ROPE + (kk - 4) * 32 + quad * 8];
    }

    // per-lane pre-swizzled global source pointers for glds staging (see v8 notes)
    int l4 = lane >> 4, l3 = lane >> 3;
    const bf16_t* kn_e = KVU + (size_t)(kt0 * 64 + w * 16 + l4) * (NH * 256) + h * 256 + ((lane & 15) ^ l4) * 8;
    const bf16_t* kn_o = KVU + (size_t)(kt0 * 64 + w * 16 + l4) * (NH * 256) + h * 256 + ((lane & 15) ^ (4 + l4)) * 8;
    const bf16_t* krp  = KR  + (size_t)(kt0 * 64 + w * 16 + l3) * ROPE + ((lane & 7) ^ l3) * 8;
    const bf16_t* vp   = Vt  + ((size_t)h * VDIM + w * 32 + l3) * T_SEQ + kt0 * 64 + ((lane & 7) ^ l3) * 8;

    bf16x8 ones;
    #pragma unroll
    for (int i = 0; i < 8; ++i) ones[i] = (bf16_t)1.0f;

    f32x4 o[8];
    #pragma unroll
    for (int nt = 0; nt < 8; ++nt) o[nt] = (f32x4){0.f, 0.f, 0.f, 0.f};
    f32x4 lacc = (f32x4){0.f, 0.f, 0.f, 0.f};

    for (int kt = kt0; kt < kt1; ++kt) {
        int kbase = kt * 64;
        // async stage K (nope+rope) and V tiles; data bypasses VGPRs entirely
        #pragma unroll
        for (int i = 0; i < 4; ++i)
            glds16(((i & 1) ? kn_o : kn_e) + (size_t)i * 4 * (NH * 256), &Kn[(w * 4 + i) * 512]);
        #pragma unroll
        for (int i = 0; i < 2; ++i)
            glds16(krp + (size_t)i * 8 * ROPE, &Kr[(w * 2 + i) * 512]);
        #pragma unroll
        for (int i = 0; i < 4; ++i)
            glds16(vp + (size_t)i * 8 * T_SEQ, &Vs[(w * 4 + i) * 512]);
        kn_e += (size_t)64 * NH * 256;
        kn_o += (size_t)64 * NH * 256;
        krp  += 64 * ROPE;
        vp   += 64;
        __syncthreads();   // vmcnt drained before barrier -> tiles visible

        // S = Q K^T : 4 col-tiles x (4 nope + 2 rope) k-steps, swizzled reads
        f32x4 S[4];
        #pragma unroll
        for (int c = 0; c < 4; ++c) S[c] = (f32x4){0.f, 0.f, 0.f, 0.f};
        #pragma unroll
        for (int kk = 0; kk < 4; ++kk) {
            #pragma unroll
            for (int c = 0; c < 4; ++c) {
                bf16x8 kf = *(const bf16x8*)&Kn[(c * 16 + l16) * 128 + (((kk * 4 + quad) ^ (l16 & 7)) * 8)];
                S[c] = __builtin_amdgcn_mfma_f32_16x16x32_bf16(qf[kk], kf, S[c], 0, 0, 0);
            }
        }
        #pragma unroll
        for (int kk = 4; kk < 6; ++kk) {
            #pragma unroll
            for (int c = 0; c < 4; ++c) {
                bf16x8 kf = *(const bf16x8*)&Kr[(c * 16 + l16) * 64 + ((((kk - 4) * 4 + quad) ^ (l16 & 7)) * 8)];
                S[c] = __builtin_amdgcn_mfma_f32_16x16x32_bf16(qf[kk], kf, S[c], 0, 0, 0);
            }
        }

        // fixed-max softmax: p = exp(s*SCALE) (bounded; shift-invariance -> additive splits)
        #pragma unroll
        for (int c = 0; c < 4; ++c) {
            #pragma unroll
            for (int j = 0; j < 4; ++j) {
                int col = kbase + c * 16 + l16;
                int grow = qbase + w * 16 + quad * 4 + j;
                float p = (col <= grow) ? __expf(S[c][j] * SCALE) : 0.f;
                Ps[w][(quad * 4 + j) * P_STRIDE + c * 16 + l16] = (bf16_t)p;
            }
        }
        __asm__ volatile("s_waitcnt lgkmcnt(0)" ::: "memory");

        bf16x8 pf0 = *(const bf16x8*)&Ps[w][l16 * P_STRIDE + quad * 8];
        bf16x8 pf1 = *(const bf16x8*)&Ps[w][l16 * P_STRIDE + 32 + quad * 8];
        lacc = __builtin_amdgcn_mfma_f32_16x16x32_bf16(pf0, ones, lacc, 0, 0, 0);
        lacc = __builtin_amdgcn_mfma_f32_16x16x32_bf16(pf1, ones, lacc, 0, 0, 0);

        // O += P V : V fragments from LDS (swizzled reads)
        #pragma unroll
        for (int kk2 = 0; kk2 < 2; ++kk2) {
            bf16x8 pf = kk2 ? pf1 : pf0;
            #pragma unroll
            for (int nt = 0; nt < 8; ++nt) {
                bf16x8 vf = *(const bf16x8*)&Vs[(nt * 16 + l16) * 64 + (((kk2 * 4 + quad) ^ (l16 & 7)) * 8)];
                o[nt] = __builtin_amdgcn_mfma_f32_16x16x32_bf16(pf, vf, o[nt], 0, 0, 0);
            }
        }
        __syncthreads();   // all reads done before next restage
    }

    // write raw partials (no normalization)
    #pragma unroll
    for (int nt = 0; nt < 8; ++nt)
        #pragma unroll
        for (int j = 0; j < 4; ++j)
            Opart[(size_t)slot * 8192 + (w * 16 + quad * 4 + j) * 128 + nt * 16 + l16] = (bf16_t)o[nt][j];
    if (l16 == 0) {
        #pragma unroll
        for (int j = 0; j < 4; ++j)
            lpart[slot * 64 + w * 16 + quad * 4 + j] = lacc[j];
    }
}

// ---------------- combine: sum partials, normalize, write ao ----------------
// grid (48, 16), block 256. Thread: row r = tid/4, 32 cols starting (tid%4)*32.
__global__ __launch_bounds__(256) void attn_combine(
    const bf16_t* __restrict__ Opart, const float* __restrict__ lpart,
    bf16_t* __restrict__ AO)
{
    int qt = blockIdx.x, h = blockIdx.y;
    int nch = qt / CHUNK + 1;
    int base = slot_base(qt, h);
    int r = threadIdx.x >> 2, c0 = (threadIdx.x & 3) * 32;

    float acc[32];
    #pragma unroll
    for (int i = 0; i < 32; ++i) acc[i] = 0.f;
    float lsum = 0.f;
    for (int ch = 0; ch < nch; ++ch) {
        int slot = base + ch;
        const bf16_t* p = &Opart[(size_t)slot * 8192 + r * 128 + c0];
        #pragma unroll
        for (int v = 0; v < 4; ++v) {
            bf16x8 u = *(const bf16x8*)&p[v * 8];
            #pragma unroll
            for (int e = 0; e < 8; ++e) acc[v * 8 + e] += (float)u[e];
        }
        lsum += lpart[slot * 64 + r];
    }
    float inv = 1.0f / lsum;
    bf16_t* dst = AO + (size_t)(qt * 64 + r) * (NH * VDIM) + h * VDIM + c0;
    #pragma unroll
    for (int v = 0; v < 4; ++v) {
        bf16_t tmp[8];
        #pragma unroll
        for (int e = 0; e < 8; ++e) tmp[e] = (bf16_t)(acc[v * 8 + e] * inv);
        *(uint4*)&dst[v * 8] = *(const uint4*)tmp;
    }
}

// ---------------- launch ----------------
extern "C" void kernel_launch(void* const* d_in, const int* in_sizes, int n_in,
                              void* d_out, int out_size, void* d_ws, size_t ws_size,
                              hipStream_t stream) {
    const float* x        = (const float*)d_in[0];
    const float* freqs    = (const float*)d_in[1];
    // d_in[2] = mask (unused; causality applied analytically)
    const float* wq_down  = (const float*)d_in[3];
    const float* q_norm_w = (const float*)d_in[4];
    const float* wq_nope  = (const float*)d_in[5];
    const float* wq_rope  = (const float*)d_in[6];
    const float* wkv_down = (const float*)d_in[7];
    const float* kv_norm_w= (const float*)d_in[8];
    const float* wkv_up   = (const float*)d_in[9];
    const float* wo       = (const float*)d_in[10];
    float* out = (float*)d_out;

    bf16_t* ws = (bf16_t*)d_ws;
    // ---- pool region (two time-disjoint views), 25,493,504 bf16 elems ----
    // A-view: pre-attention transients
    bf16_t* xb     = ws;                     // 3072*2048
    bf16_t* wqd_t  = xb     + 6291456;       // [1536][2048]  \ contiguous pair ->
    bf16_t* wkvd_t = wqd_t  + 3145728;       // [576][2048]   / fused Bt, N=2112
    bf16_t* wqn_t  = wkvd_t + 1179648;       // [2048][1536]  \ contiguous pair ->
    bf16_t* wqr_t  = wqn_t  + 3145728;       // [1024][1536]  / fused Bt, N=3072
    bf16_t* wkvu_t = wqr_t  + 1572864;       // [4096][512]
    bf16_t* t1kv   = wkvu_t + 2097152;       // [3072][2112] fused q_lat|c_kv|k_rope
    bf16_t* ckvn   = t1kv   + 6488064;       // 3072*512  (ends at 25,493,504)
    // B-view: attention partials + ao
    bf16_t* Opart  = ws;                     // 1920 slots * 8192
    float*  lpart  = (float*)(ws + 15728640);// 1920 * 64 fp32
    bf16_t* ao     = ws + 15728640 + 245760; // 3072*2048
    // ---- tail region (long-lived) ----
    bf16_t* wo_t   = ws    + 25493504;       // [2048][2048]
    bf16_t* kr     = wo_t  + 4194304;        // 3072*64
    bf16_t* qnr    = kr    + 196608;         // [3072][3072] fused q_nope|q_rope
    bf16_t* kvu    = qnr   + 9437184;        // 3072*4096
    bf16_t* vt     = kvu   + 12582912;       // [16][128][3072]  (total 58,195,968)

    // converts + weight transposes
    f2b_kernel<<<T_SEQ * DIM / 4 / 256, 256, 0, stream>>>(x, xb, T_SEQ * DIM);
    transp_kernel<<<dim3(QLORA / 32, DIM / 32), 256, 0, stream>>>(wq_down, wqd_t, DIM, QLORA);
    transp_kernel<<<dim3((KVLORA + ROPE) / 32, DIM / 32), 256, 0, stream>>>(wkv_down, wkvd_t, DIM, KVLORA + ROPE);
    transp_kernel<<<dim3(NH * NOPE / 32, QLORA / 32), 256, 0, stream>>>(wq_nope, wqn_t, QLORA, NH * NOPE);
    transp_kernel<<<dim3(NH * ROPE / 32, QLORA / 32), 256, 0, stream>>>(wq_rope, wqr_t, QLORA, NH * ROPE);
    transp_kernel<<<dim3(NH * 256 / 32, KVLORA / 32), 256, 0, stream>>>(wkv_up, wkvu_t, KVLORA, NH * 256);
    transp_kernel<<<dim3(DIM / 32, DIM / 32), 256, 0, stream>>>(wo, wo_t, DIM, DIM);

    // fused down-projection: [q_lat | c_kv | k_rope], N=2112, grid 17x24=408
    gemm_mfma<<<dim3(17, T_SEQ / 128), 256, 0, stream>>>(
        xb, wqd_t, nullptr, t1kv, T_SEQ, 2112, DIM, DIM, DIM, T1KV_LD, 0);

    rmsnorm_rows<<<T_SEQ, 256, 0, stream>>>(t1kv, q_norm_w, QLORA, T1KV_LD);
    kv_post<<<T_SEQ, 256, 0, stream>>>(t1kv + QLORA, kv_norm_w, freqs, ckvn, kr);

    // fused q up-projection: [q_nope | q_rope], N=3072, grid 24x24=576
    gemm_mfma<<<dim3(24, T_SEQ / 128), 256, 0, stream>>>(
        t1kv, wqn_t, nullptr, qnr, T_SEQ, 3072, QLORA, T1KV_LD, QLORA, QNR_LD, 0);
    rope_q<<<(T_SEQ * NH * 32 + 255) / 256, 256, 0, stream>>>(qnr + NH * NOPE, freqs);

    // kv up-projection, grid 32x24=768
    gemm_mfma<<<dim3(NH * 256 / 128, T_SEQ / 128), 256, 0, stream>>>(
        ckvn, wkvu_t, nullptr, kvu, T_SEQ, NH * 256, KVLORA, KVLORA, KVLORA, NH * 256, 0);

    // V transpose for attention B-operand
    vt_transp<<<dim3(T_SEQ / 32, VDIM / 32, NH), 256, 0, stream>>>(kvu, vt);

    // split-K attention (longest-first dispatch) + combine
    attn_v12<<<dim3(T_SEQ / 64, 4, NH), 256, 0, stream>>>(qnr, kvu, kr, vt, Opart, lpart);
    attn_combine<<<dim3(T_SEQ / 64, NH), 256, 0, stream>>>(Opart, lpart, ao);

    // output projection (fp32 out)
    gemm_mfma<<<dim3(DIM / 128, T_SEQ / 128), 256, 0, stream>>>(
        ao, wo_t, out, nullptr, T_SEQ, DIM, DIM, DIM, DIM, DIM, 1);
}